// Round 6
// baseline (5019.943 us; speedup 1.0000x reference)
//
#include <hip/hip_runtime.h>
#include <hip/hip_fp16.h>
#include <hip/hip_bf16.h>

#define DM   256      // d_model
#define DI   512      // d_inner
#define TG   768      // 3*d_model
#define TSEQ 4096
#define NB   8
#define MTOT (NB*TSEQ) // 32768

typedef _Float16 h2f  __attribute__((ext_vector_type(2)));
typedef _Float16 h8f  __attribute__((ext_vector_type(8)));
typedef _Float16 w128 __attribute__((ext_vector_type(128)));   // 64 VGPRs, pure SSA

// ---------------- Phase 1: tiled fp32 GEMM, C = act(A @ W^T + bias) in fp16 ----
template<bool A_HALF, bool GELU_ACT>
__global__ __launch_bounds__(256) void gemm_bias(
    const void* __restrict__ Ap, const float* __restrict__ W,
    const float* __restrict__ bias, __half* __restrict__ C,
    int M, int N, int K)
{
  __shared__ float As[16][132];   // transposed: [k][m]
  __shared__ float Ws[16][132];   // transposed: [k][n]
  const int tid = threadIdx.x;
  const int tx = tid & 15, ty = tid >> 4;
  const int m0 = blockIdx.y * 128;
  const int n0 = blockIdx.x * 128;

  float acc[8][8] = {};

  for (int k0 = 0; k0 < K; k0 += 16) {
    if constexpr (A_HALF) {
      const __half* A = (const __half*)Ap;
      int r = tid >> 1, seg = (tid & 1) * 8;
      float4 raw = *(const float4*)(A + (size_t)(m0 + r) * K + k0 + seg);
      const __half* hv = (const __half*)&raw;
      #pragma unroll
      for (int q = 0; q < 8; q++) As[seg + q][r] = __half2float(hv[q]);
    } else {
      const float* A = (const float*)Ap;
      #pragma unroll
      for (int rep = 0; rep < 2; rep++) {
        int r = (tid >> 2) + rep * 64;
        int seg = (tid & 3) * 4;
        float4 v = *(const float4*)(A + (size_t)(m0 + r) * K + k0 + seg);
        As[seg + 0][r] = v.x; As[seg + 1][r] = v.y;
        As[seg + 2][r] = v.z; As[seg + 3][r] = v.w;
      }
    }
    #pragma unroll
    for (int rep = 0; rep < 2; rep++) {
      int r = (tid >> 2) + rep * 64;
      int seg = (tid & 3) * 4;
      float4 v = *(const float4*)(W + (size_t)(n0 + r) * K + k0 + seg);
      Ws[seg + 0][r] = v.x; Ws[seg + 1][r] = v.y;
      Ws[seg + 2][r] = v.z; Ws[seg + 3][r] = v.w;
    }
    __syncthreads();
    #pragma unroll
    for (int kk = 0; kk < 16; ++kk) {
      float a[8], b[8];
      *(float4*)&a[0] = *(const float4*)&As[kk][ty * 8];
      *(float4*)&a[4] = *(const float4*)&As[kk][ty * 8 + 4];
      *(float4*)&b[0] = *(const float4*)&Ws[kk][tx * 8];
      *(float4*)&b[4] = *(const float4*)&Ws[kk][tx * 8 + 4];
      #pragma unroll
      for (int i = 0; i < 8; i++)
        #pragma unroll
        for (int j = 0; j < 8; j++)
          acc[i][j] += a[i] * b[j];
    }
    __syncthreads();
  }

  #pragma unroll
  for (int i = 0; i < 8; i++) {
    int m = m0 + ty * 8 + i;
    #pragma unroll
    for (int j = 0; j < 8; j++) {
      int n = n0 + tx * 8 + j;
      float v = acc[i][j] + bias[n];
      if constexpr (GELU_ACT) {
        v = 0.5f * v * (1.0f + erff(v * 0.70710678118654752f));  // exact GELU
      }
      C[(size_t)m * N + n] = __float2half(v);
    }
  }
}

// ---------------- DPP pair butterfly (lane 2u <-> 2u+1), VALU only -----------
__device__ __forceinline__ float dpp_xor1_add(float v) {
  int i = __builtin_bit_cast(int, v);
  int s = __builtin_amdgcn_update_dpp(i, i, 0xB1, 0xF, 0xF, true); // quad_perm [1,0,3,2]
  return v + __builtin_bit_cast(float, s);
}

// ---- literal-index macros (shufflevector/subscript need parse-time consts) --
#define LDW(dst, src, B) {                                         \
    float4 f_ = *(const float4*)((src) + 4 * (B));                 \
    dst[4*(B)+0] = (_Float16)f_.x; dst[4*(B)+1] = (_Float16)f_.y;  \
    dst[4*(B)+2] = (_Float16)f_.z; dst[4*(B)+3] = (_Float16)f_.w; }

#define REP32(M, d, s) \
  M(d,s,0)  M(d,s,1)  M(d,s,2)  M(d,s,3)  M(d,s,4)  M(d,s,5)  M(d,s,6)  M(d,s,7)  \
  M(d,s,8)  M(d,s,9)  M(d,s,10) M(d,s,11) M(d,s,12) M(d,s,13) M(d,s,14) M(d,s,15) \
  M(d,s,16) M(d,s,17) M(d,s,18) M(d,s,19) M(d,s,20) M(d,s,21) M(d,s,22) M(d,s,23) \
  M(d,s,24) M(d,s,25) M(d,s,26) M(d,s,27) M(d,s,28) M(d,s,29) M(d,s,30) M(d,s,31)

#define WPAIR(W_, B, m) __builtin_shufflevector(W_, W_, 8*(B)+2*(m), 8*(B)+2*(m)+1)

#define DSTEP(B) {                                                        \
    h8f hh_ = hp[B];                                                      \
    h2f c0_ = __builtin_shufflevector(hh_, hh_, 0, 1);                    \
    h2f c1_ = __builtin_shufflevector(hh_, hh_, 2, 3);                    \
    h2f c2_ = __builtin_shufflevector(hh_, hh_, 4, 5);                    \
    h2f c3_ = __builtin_shufflevector(hh_, hh_, 6, 7);                    \
    ar0 = __builtin_amdgcn_fdot2(WPAIR(wr,B,0), c0_, ar0, false);         \
    az0 = __builtin_amdgcn_fdot2(WPAIR(wz,B,0), c0_, az0, false);         \
    an0 = __builtin_amdgcn_fdot2(WPAIR(wn,B,0), c0_, an0, false);         \
    ar1 = __builtin_amdgcn_fdot2(WPAIR(wr,B,1), c1_, ar1, false);         \
    az1 = __builtin_amdgcn_fdot2(WPAIR(wz,B,1), c1_, az1, false);         \
    an1 = __builtin_amdgcn_fdot2(WPAIR(wn,B,1), c1_, an1, false);         \
    ar0 = __builtin_amdgcn_fdot2(WPAIR(wr,B,2), c2_, ar0, false);         \
    az0 = __builtin_amdgcn_fdot2(WPAIR(wz,B,2), c2_, az0, false);         \
    an0 = __builtin_amdgcn_fdot2(WPAIR(wn,B,2), c2_, an0, false);         \
    ar1 = __builtin_amdgcn_fdot2(WPAIR(wr,B,3), c3_, ar1, false);         \
    az1 = __builtin_amdgcn_fdot2(WPAIR(wz,B,3), c3_, az1, false);         \
    an1 = __builtin_amdgcn_fdot2(WPAIR(wn,B,3), c3_, an1, false); }

#define REP16S(M) \
  M(0) M(1) M(2) M(3) M(4) M(5) M(6) M(7) M(8) M(9) M(10) M(11) M(12) M(13) M(14) M(15)

// ---------------- Phase 2: persistent GRU scan, one block per batch ----------
// ROUND-5 LESSON: C arrays of weights are allocas that AMDGPU promote-alloca
// refuses to register-promote (VGPR_Count=128 CHOSEN below a 256 budget =>
// arrays lived in scratch from IR, ~3000cy/step of L2 spill reloads). Fix:
// hold weights as ext_vector_type(128) SSA values (64 VGPRs each, no alloca
// possible), all accesses via literal-index macros.
__global__ __launch_bounds__(512, 1) __attribute__((amdgpu_waves_per_eu(2, 2)))
void gru_scan(
    const __half* __restrict__ gx,   // [B, T, 768] fp16 (includes b_ih)
    const float*  __restrict__ Whh,  // [768, 256]
    const float*  __restrict__ bhh,  // [768]
    float* __restrict__ out)         // [B, T, 256]
{
  const int b = blockIdx.x;
  const int j = threadIdx.x;   // 0..511
  const int u = j >> 1;        // hidden unit 0..255
  const int p = j & 1;         // K-half

  // [buf][half][128 data + 8 pad]: 272B half-stride keeps the pair's two
  // broadcast addresses in different bank groups (round-5: conflicts -> 0).
  __shared__ __align__(16) _Float16 hbuf[2][2][136];

  // ---- weights: 3 gate rows x 128 cols (this lane's K-half), SSA vectors ----
  w128 wr, wz, wn;
  {
    const float* rr = Whh + (size_t)u * DM + p * 128;
    const float* rz = rr + (size_t)DM * DM;
    const float* rn = rz + (size_t)DM * DM;
    REP32(LDW, wr, rr)
    REP32(LDW, wz, rz)
    REP32(LDW, wn, rn)
  }
  const float br = bhh[u];
  const float bz = bhh[DM + u];
  const float bn = bhh[2 * DM + u];
  float hloc = 0.0f;

  if (j < DM) hbuf[0][j >> 7][j & 127] = (_Float16)0.0f;
  __syncthreads();

  const __half* gp = gx + (size_t)b * TSEQ * TG;
  float* outb = out + (size_t)b * TSEQ * DM;

  float gxr = __half2float(gp[u]);
  float gxz = __half2float(gp[DM + u]);
  float gxn = __half2float(gp[2 * DM + u]);

  for (int t = 0; t < TSEQ; ++t) {
    const int cur = t & 1;
    const h8f* hp = (const h8f*)(&hbuf[cur][p][0]);

    // prefetch next timestep's gx (hides under the dot loop)
    float nr = 0.f, nz = 0.f, nn = 0.f;
    if (t + 1 < TSEQ) {
      const __half* g1 = gp + TG;
      nr = __half2float(g1[u]);
      nz = __half2float(g1[DM + u]);
      nn = __half2float(g1[2 * DM + u]);
    }

    // ---- partial dots over this lane's 128 columns (96 fdot2) ----
    float ar0 = 0.f, ar1 = 0.f, az0 = 0.f, az1 = 0.f, an0 = 0.f, an1 = 0.f;
    REP16S(DSTEP)

    // ---- pair butterfly: both lanes get the full 256-wide sums ----
    float ar = dpp_xor1_add(ar0 + ar1);
    float az = dpp_xor1_add(az0 + az1);
    float an = dpp_xor1_add(an0 + an1);

    // ---- gates (redundant on both pair lanes; no LDS exchange) ----
    float r = __builtin_amdgcn_rcpf(1.0f + __expf(-(gxr + ar + br)));
    float z = __builtin_amdgcn_rcpf(1.0f + __expf(-(gxz + az + bz)));
    float a = gxn + r * (an + bn);
    float e = __expf(-2.0f * __builtin_fabsf(a));              // in (0,1]
    float n = __builtin_copysignf((1.0f - e) * __builtin_amdgcn_rcpf(1.0f + e), a);
    float hnew = n + z * (hloc - n);
    hloc = hnew;

    if (p == 0) {
      hbuf[cur ^ 1][u >> 7][u & 127] = (_Float16)hnew;
      outb[(size_t)t * DM + u] = hnew;
    }
    __syncthreads();   // writes to buf^1 visible before next iteration reads

    gp += TG;
    gxr = nr; gxz = nz; gxn = nn;
  }
}

extern "C" void kernel_launch(void* const* d_in, const int* in_sizes, int n_in,
                              void* d_out, int out_size, void* d_ws, size_t ws_size,
                              hipStream_t stream) {
  const float* x   = (const float*)d_in[0];
  const float* W1  = (const float*)d_in[1];
  const float* b1  = (const float*)d_in[2];
  const float* Wih = (const float*)d_in[3];
  const float* bih = (const float*)d_in[4];
  const float* Whh = (const float*)d_in[5];
  const float* bhh = (const float*)d_in[6];
  float* out = (float*)d_out;

  char* ws = (char*)d_ws;
  __half* h  = (__half*)ws;                                   // [32768,512] fp16
  size_t h_bytes = (size_t)MTOT * DI * sizeof(__half);
  h_bytes = (h_bytes + 255) & ~(size_t)255;
  __half* gxbuf = (__half*)(ws + h_bytes);                    // [32768,768] fp16

  dim3 blk(256);
  gemm_bias<false, true><<<dim3(DI / 128, MTOT / 128), blk, 0, stream>>>(
      x, W1, b1, h, MTOT, DI, DM);
  gemm_bias<true, false><<<dim3(TG / 128, MTOT / 128), blk, 0, stream>>>(
      h, Wih, bih, gxbuf, MTOT, TG, DI);
  gru_scan<<<NB, 512, 0, stream>>>(gxbuf, Whh, bhh, out);
}

// Round 7
// 4997.152 us; speedup vs baseline: 1.0046x; 1.0046x over previous
//
#include <hip/hip_runtime.h>
#include <hip/hip_fp16.h>
#include <hip/hip_bf16.h>

#define DM   256      // d_model
#define DI   512      // d_inner
#define TG   768      // 3*d_model
#define TSEQ 4096
#define NB   8
#define MTOT (NB*TSEQ) // 32768

typedef _Float16 h2f  __attribute__((ext_vector_type(2)));
typedef _Float16 h8f  __attribute__((ext_vector_type(8)));

// ---------------- Phase 1: tiled fp32 GEMM, C = act(A @ W^T + bias) in fp16 ----
template<bool A_HALF, bool GELU_ACT>
__global__ __launch_bounds__(256) void gemm_bias(
    const void* __restrict__ Ap, const float* __restrict__ W,
    const float* __restrict__ bias, __half* __restrict__ C,
    int M, int N, int K)
{
  __shared__ float As[16][132];   // transposed: [k][m]
  __shared__ float Ws[16][132];   // transposed: [k][n]
  const int tid = threadIdx.x;
  const int tx = tid & 15, ty = tid >> 4;
  const int m0 = blockIdx.y * 128;
  const int n0 = blockIdx.x * 128;

  float acc[8][8] = {};

  for (int k0 = 0; k0 < K; k0 += 16) {
    if constexpr (A_HALF) {
      const __half* A = (const __half*)Ap;
      int r = tid >> 1, seg = (tid & 1) * 8;
      float4 raw = *(const float4*)(A + (size_t)(m0 + r) * K + k0 + seg);
      const __half* hv = (const __half*)&raw;
      #pragma unroll
      for (int q = 0; q < 8; q++) As[seg + q][r] = __half2float(hv[q]);
    } else {
      const float* A = (const float*)Ap;
      #pragma unroll
      for (int rep = 0; rep < 2; rep++) {
        int r = (tid >> 2) + rep * 64;
        int seg = (tid & 3) * 4;
        float4 v = *(const float4*)(A + (size_t)(m0 + r) * K + k0 + seg);
        As[seg + 0][r] = v.x; As[seg + 1][r] = v.y;
        As[seg + 2][r] = v.z; As[seg + 3][r] = v.w;
      }
    }
    #pragma unroll
    for (int rep = 0; rep < 2; rep++) {
      int r = (tid >> 2) + rep * 64;
      int seg = (tid & 3) * 4;
      float4 v = *(const float4*)(W + (size_t)(n0 + r) * K + k0 + seg);
      Ws[seg + 0][r] = v.x; Ws[seg + 1][r] = v.y;
      Ws[seg + 2][r] = v.z; Ws[seg + 3][r] = v.w;
    }
    __syncthreads();
    #pragma unroll
    for (int kk = 0; kk < 16; ++kk) {
      float a[8], b[8];
      *(float4*)&a[0] = *(const float4*)&As[kk][ty * 8];
      *(float4*)&a[4] = *(const float4*)&As[kk][ty * 8 + 4];
      *(float4*)&b[0] = *(const float4*)&Ws[kk][tx * 8];
      *(float4*)&b[4] = *(const float4*)&Ws[kk][tx * 8 + 4];
      #pragma unroll
      for (int i = 0; i < 8; i++)
        #pragma unroll
        for (int j = 0; j < 8; j++)
          acc[i][j] += a[i] * b[j];
    }
    __syncthreads();
  }

  #pragma unroll
  for (int i = 0; i < 8; i++) {
    int m = m0 + ty * 8 + i;
    #pragma unroll
    for (int j = 0; j < 8; j++) {
      int n = n0 + tx * 8 + j;
      float v = acc[i][j] + bias[n];
      if constexpr (GELU_ACT) {
        v = 0.5f * v * (1.0f + erff(v * 0.70710678118654752f));  // exact GELU
      }
      C[(size_t)m * N + n] = __float2half(v);
    }
  }
}

// ---------------- DPP pair butterfly (lane 2u <-> 2u+1), VALU only -----------
__device__ __forceinline__ float dpp_xor1_add(float v) {
  int i = __builtin_bit_cast(int, v);
  int s = __builtin_amdgcn_update_dpp(i, i, 0xB1, 0xF, 0xF, true); // quad_perm [1,0,3,2]
  return v + __builtin_bit_cast(float, s);
}

// ---- weights as 192 NAMED scalar h2f locals --------------------------------
// ROUND-6 LESSON: arrays AND wide ext-vectors of weights end up in AGPRs
// (64-consecutive-reg tuples can't be colored into the 256 arch-VGPR slots);
// v_dot2 can't read AGPRs, so the compiler inserted ~384 v_accvgpr_read per
// step (VALU 71% busy on active CUs, 2700cy/step, VGPR_Count=128 = arch only).
// Individually named h2f scalars have no tuple constraint: ~232 live regs fit
// the arch file at 2 waves/SIMD, fdot2 reads them in place.
#define D3(i) h2f wr##i, wz##i, wn##i;
#define L3(i) { float2 f_;                                                     \
    f_ = *(const float2*)(rr + 2*(i)); wr##i[0]=(_Float16)f_.x; wr##i[1]=(_Float16)f_.y; \
    f_ = *(const float2*)(rz + 2*(i)); wz##i[0]=(_Float16)f_.x; wz##i[1]=(_Float16)f_.y; \
    f_ = *(const float2*)(rn + 2*(i)); wn##i[0]=(_Float16)f_.x; wn##i[1]=(_Float16)f_.y; }

#define REP64(M) \
  M(0)  M(1)  M(2)  M(3)  M(4)  M(5)  M(6)  M(7)  \
  M(8)  M(9)  M(10) M(11) M(12) M(13) M(14) M(15) \
  M(16) M(17) M(18) M(19) M(20) M(21) M(22) M(23) \
  M(24) M(25) M(26) M(27) M(28) M(29) M(30) M(31) \
  M(32) M(33) M(34) M(35) M(36) M(37) M(38) M(39) \
  M(40) M(41) M(42) M(43) M(44) M(45) M(46) M(47) \
  M(48) M(49) M(50) M(51) M(52) M(53) M(54) M(55) \
  M(56) M(57) M(58) M(59) M(60) M(61) M(62) M(63)

#define REP64B4(M) /* with sched_barrier every 4 to bound loads in flight */ \
  M(0)  M(1)  M(2)  M(3)  SB M(4)  M(5)  M(6)  M(7)  SB \
  M(8)  M(9)  M(10) M(11) SB M(12) M(13) M(14) M(15) SB \
  M(16) M(17) M(18) M(19) SB M(20) M(21) M(22) M(23) SB \
  M(24) M(25) M(26) M(27) SB M(28) M(29) M(30) M(31) SB \
  M(32) M(33) M(34) M(35) SB M(36) M(37) M(38) M(39) SB \
  M(40) M(41) M(42) M(43) SB M(44) M(45) M(46) M(47) SB \
  M(48) M(49) M(50) M(51) SB M(52) M(53) M(54) M(55) SB \
  M(56) M(57) M(58) M(59) SB M(60) M(61) M(62) M(63) SB
#define SB __builtin_amdgcn_sched_barrier(0);

#define DSTEP(B, I0, I1, I2, I3) {                                        \
    h8f hh_ = hp[B];                                                      \
    h2f c0_ = __builtin_shufflevector(hh_, hh_, 0, 1);                    \
    h2f c1_ = __builtin_shufflevector(hh_, hh_, 2, 3);                    \
    h2f c2_ = __builtin_shufflevector(hh_, hh_, 4, 5);                    \
    h2f c3_ = __builtin_shufflevector(hh_, hh_, 6, 7);                    \
    ar0 = __builtin_amdgcn_fdot2(wr##I0, c0_, ar0, false);                \
    az0 = __builtin_amdgcn_fdot2(wz##I0, c0_, az0, false);                \
    an0 = __builtin_amdgcn_fdot2(wn##I0, c0_, an0, false);                \
    ar1 = __builtin_amdgcn_fdot2(wr##I1, c1_, ar1, false);                \
    az1 = __builtin_amdgcn_fdot2(wz##I1, c1_, az1, false);                \
    an1 = __builtin_amdgcn_fdot2(wn##I1, c1_, an1, false);                \
    ar0 = __builtin_amdgcn_fdot2(wr##I2, c2_, ar0, false);                \
    az0 = __builtin_amdgcn_fdot2(wz##I2, c2_, az0, false);                \
    an0 = __builtin_amdgcn_fdot2(wn##I2, c2_, an0, false);                \
    ar1 = __builtin_amdgcn_fdot2(wr##I3, c3_, ar1, false);                \
    az1 = __builtin_amdgcn_fdot2(wz##I3, c3_, az1, false);                \
    an1 = __builtin_amdgcn_fdot2(wn##I3, c3_, an1, false); }

// ---------------- Phase 2: persistent GRU scan, one block per batch ----------
__global__ __launch_bounds__(512, 1) __attribute__((amdgpu_waves_per_eu(2, 2)))
void gru_scan(
    const __half* __restrict__ gx,   // [B, T, 768] fp16 (includes b_ih)
    const float*  __restrict__ Whh,  // [768, 256]
    const float*  __restrict__ bhh,  // [768]
    float* __restrict__ out)         // [B, T, 256]
{
  const int b = blockIdx.x;
  const int j = threadIdx.x;   // 0..511
  const int u = j >> 1;        // hidden unit 0..255
  const int p = j & 1;         // K-half

  // [buf][half][128 data + 8 pad]: 272B half-stride keeps the pair's two
  // broadcast addresses in different bank groups (round-5: conflicts -> 0).
  __shared__ __align__(16) _Float16 hbuf[2][2][136];

  // ---- weights: 3 gate rows x 128 cols (this lane's K-half) ----
  REP64(D3)
  {
    const float* rr = Whh + (size_t)u * DM + p * 128;
    const float* rz = rr + (size_t)DM * DM;
    const float* rn = rz + (size_t)DM * DM;
    REP64B4(L3)
  }
  const float br = bhh[u];
  const float bz = bhh[DM + u];
  const float bn = bhh[2 * DM + u];
  float hloc = 0.0f;

  if (j < DM) hbuf[0][j >> 7][j & 127] = (_Float16)0.0f;
  __syncthreads();

  const __half* gp = gx + (size_t)b * TSEQ * TG;
  float* outb = out + (size_t)b * TSEQ * DM;

  float gxr = __half2float(gp[u]);
  float gxz = __half2float(gp[DM + u]);
  float gxn = __half2float(gp[2 * DM + u]);

  for (int t = 0; t < TSEQ; ++t) {
    const int cur = t & 1;
    const h8f* hp = (const h8f*)(&hbuf[cur][p][0]);

    // prefetch next timestep's gx (hides under the dot loop)
    float nr = 0.f, nz = 0.f, nn = 0.f;
    if (t + 1 < TSEQ) {
      const __half* g1 = gp + TG;
      nr = __half2float(g1[u]);
      nz = __half2float(g1[DM + u]);
      nn = __half2float(g1[2 * DM + u]);
    }

    // ---- partial dots over this lane's 128 columns (192 fdot2) ----
    float ar0 = 0.f, ar1 = 0.f, az0 = 0.f, az1 = 0.f, an0 = 0.f, an1 = 0.f;
    DSTEP(0,  0,  1,  2,  3)  DSTEP(1,  4,  5,  6,  7)
    DSTEP(2,  8,  9,  10, 11) DSTEP(3,  12, 13, 14, 15)
    DSTEP(4,  16, 17, 18, 19) DSTEP(5,  20, 21, 22, 23)
    DSTEP(6,  24, 25, 26, 27) DSTEP(7,  28, 29, 30, 31)
    DSTEP(8,  32, 33, 34, 35) DSTEP(9,  36, 37, 38, 39)
    DSTEP(10, 40, 41, 42, 43) DSTEP(11, 44, 45, 46, 47)
    DSTEP(12, 48, 49, 50, 51) DSTEP(13, 52, 53, 54, 55)
    DSTEP(14, 56, 57, 58, 59) DSTEP(15, 60, 61, 62, 63)

    // ---- pair butterfly: both lanes get the full 256-wide sums ----
    float ar = dpp_xor1_add(ar0 + ar1);
    float az = dpp_xor1_add(az0 + az1);
    float an = dpp_xor1_add(an0 + an1);

    // ---- gates (redundant on both pair lanes; no LDS exchange) ----
    float r = __builtin_amdgcn_rcpf(1.0f + __expf(-(gxr + ar + br)));
    float z = __builtin_amdgcn_rcpf(1.0f + __expf(-(gxz + az + bz)));
    float a = gxn + r * (an + bn);
    float e = __expf(-2.0f * __builtin_fabsf(a));              // in (0,1]
    float n = __builtin_copysignf((1.0f - e) * __builtin_amdgcn_rcpf(1.0f + e), a);
    float hnew = n + z * (hloc - n);
    hloc = hnew;

    if (p == 0) {
      hbuf[cur ^ 1][u >> 7][u & 127] = (_Float16)hnew;
      outb[(size_t)t * DM + u] = hnew;
    }
    __syncthreads();   // writes to buf^1 visible before next iteration reads

    gp += TG;
    gxr = nr; gxz = nz; gxn = nn;
  }
}

extern "C" void kernel_launch(void* const* d_in, const int* in_sizes, int n_in,
                              void* d_out, int out_size, void* d_ws, size_t ws_size,
                              hipStream_t stream) {
  const float* x   = (const float*)d_in[0];
  const float* W1  = (const float*)d_in[1];
  const float* b1  = (const float*)d_in[2];
  const float* Wih = (const float*)d_in[3];
  const float* bih = (const float*)d_in[4];
  const float* Whh = (const float*)d_in[5];
  const float* bhh = (const float*)d_in[6];
  float* out = (float*)d_out;

  char* ws = (char*)d_ws;
  __half* h  = (__half*)ws;                                   // [32768,512] fp16
  size_t h_bytes = (size_t)MTOT * DI * sizeof(__half);
  h_bytes = (h_bytes + 255) & ~(size_t)255;
  __half* gxbuf = (__half*)(ws + h_bytes);                    // [32768,768] fp16

  dim3 blk(256);
  gemm_bias<false, true><<<dim3(DI / 128, MTOT / 128), blk, 0, stream>>>(
      x, W1, b1, h, MTOT, DI, DM);
  gemm_bias<true, false><<<dim3(TG / 128, MTOT / 128), blk, 0, stream>>>(
      h, Wih, bih, gxbuf, MTOT, TG, DI);
  gru_scan<<<NB, 512, 0, stream>>>(gxbuf, Whh, bhh, out);
}

// Round 8
// 4996.384 us; speedup vs baseline: 1.0047x; 1.0002x over previous
//
#include <hip/hip_runtime.h>
#include <hip/hip_fp16.h>
#include <hip/hip_bf16.h>

#define DM   256      // d_model
#define DI   512      // d_inner
#define TG   768      // 3*d_model
#define TSEQ 4096
#define NB   8
#define MTOT (NB*TSEQ) // 32768

typedef _Float16 h2f  __attribute__((ext_vector_type(2)));
typedef _Float16 h8f  __attribute__((ext_vector_type(8)));

// ---------------- Phase 1: tiled fp32 GEMM, C = act(A @ W^T + bias) in fp16 ----
template<bool A_HALF, bool GELU_ACT>
__global__ __launch_bounds__(256) void gemm_bias(
    const void* __restrict__ Ap, const float* __restrict__ W,
    const float* __restrict__ bias, __half* __restrict__ C,
    int M, int N, int K)
{
  __shared__ float As[16][132];   // transposed: [k][m]
  __shared__ float Ws[16][132];   // transposed: [k][n]
  const int tid = threadIdx.x;
  const int tx = tid & 15, ty = tid >> 4;
  const int m0 = blockIdx.y * 128;
  const int n0 = blockIdx.x * 128;

  float acc[8][8] = {};

  for (int k0 = 0; k0 < K; k0 += 16) {
    if constexpr (A_HALF) {
      const __half* A = (const __half*)Ap;
      int r = tid >> 1, seg = (tid & 1) * 8;
      float4 raw = *(const float4*)(A + (size_t)(m0 + r) * K + k0 + seg);
      const __half* hv = (const __half*)&raw;
      #pragma unroll
      for (int q = 0; q < 8; q++) As[seg + q][r] = __half2float(hv[q]);
    } else {
      const float* A = (const float*)Ap;
      #pragma unroll
      for (int rep = 0; rep < 2; rep++) {
        int r = (tid >> 2) + rep * 64;
        int seg = (tid & 3) * 4;
        float4 v = *(const float4*)(A + (size_t)(m0 + r) * K + k0 + seg);
        As[seg + 0][r] = v.x; As[seg + 1][r] = v.y;
        As[seg + 2][r] = v.z; As[seg + 3][r] = v.w;
      }
    }
    #pragma unroll
    for (int rep = 0; rep < 2; rep++) {
      int r = (tid >> 2) + rep * 64;
      int seg = (tid & 3) * 4;
      float4 v = *(const float4*)(W + (size_t)(n0 + r) * K + k0 + seg);
      Ws[seg + 0][r] = v.x; Ws[seg + 1][r] = v.y;
      Ws[seg + 2][r] = v.z; Ws[seg + 3][r] = v.w;
    }
    __syncthreads();
    #pragma unroll
    for (int kk = 0; kk < 16; ++kk) {
      float a[8], b[8];
      *(float4*)&a[0] = *(const float4*)&As[kk][ty * 8];
      *(float4*)&a[4] = *(const float4*)&As[kk][ty * 8 + 4];
      *(float4*)&b[0] = *(const float4*)&Ws[kk][tx * 8];
      *(float4*)&b[4] = *(const float4*)&Ws[kk][tx * 8 + 4];
      #pragma unroll
      for (int i = 0; i < 8; i++)
        #pragma unroll
        for (int j = 0; j < 8; j++)
          acc[i][j] += a[i] * b[j];
    }
    __syncthreads();
  }

  #pragma unroll
  for (int i = 0; i < 8; i++) {
    int m = m0 + ty * 8 + i;
    #pragma unroll
    for (int j = 0; j < 8; j++) {
      int n = n0 + tx * 8 + j;
      float v = acc[i][j] + bias[n];
      if constexpr (GELU_ACT) {
        v = 0.5f * v * (1.0f + erff(v * 0.70710678118654752f));  // exact GELU
      }
      C[(size_t)m * N + n] = __float2half(v);
    }
  }
}

// ---------------- DPP pair butterfly (lane 2u <-> 2u+1), VALU only -----------
__device__ __forceinline__ float dpp_xor1_add(float v) {
  int i = __builtin_bit_cast(int, v);
  int s = __builtin_amdgcn_update_dpp(i, i, 0xB1, 0xF, 0xF, true); // quad_perm [1,0,3,2]
  return v + __builtin_bit_cast(float, s);
}

// ---- weights as 192 NAMED scalar h2f locals --------------------------------
#define D3(i) h2f wr##i, wz##i, wn##i;
#define L3(i) { float2 f_;                                                     \
    f_ = *(const float2*)(rr + 2*(i)); wr##i[0]=(_Float16)f_.x; wr##i[1]=(_Float16)f_.y; \
    f_ = *(const float2*)(rz + 2*(i)); wz##i[0]=(_Float16)f_.x; wz##i[1]=(_Float16)f_.y; \
    f_ = *(const float2*)(rn + 2*(i)); wn##i[0]=(_Float16)f_.x; wn##i[1]=(_Float16)f_.y; }

#define REP64(M) \
  M(0)  M(1)  M(2)  M(3)  M(4)  M(5)  M(6)  M(7)  \
  M(8)  M(9)  M(10) M(11) M(12) M(13) M(14) M(15) \
  M(16) M(17) M(18) M(19) M(20) M(21) M(22) M(23) \
  M(24) M(25) M(26) M(27) M(28) M(29) M(30) M(31) \
  M(32) M(33) M(34) M(35) M(36) M(37) M(38) M(39) \
  M(40) M(41) M(42) M(43) M(44) M(45) M(46) M(47) \
  M(48) M(49) M(50) M(51) M(52) M(53) M(54) M(55) \
  M(56) M(57) M(58) M(59) M(60) M(61) M(62) M(63)

#define REP64B4(M) /* with sched_barrier every 4 to bound loads in flight */ \
  M(0)  M(1)  M(2)  M(3)  SB M(4)  M(5)  M(6)  M(7)  SB \
  M(8)  M(9)  M(10) M(11) SB M(12) M(13) M(14) M(15) SB \
  M(16) M(17) M(18) M(19) SB M(20) M(21) M(22) M(23) SB \
  M(24) M(25) M(26) M(27) SB M(28) M(29) M(30) M(31) SB \
  M(32) M(33) M(34) M(35) SB M(36) M(37) M(38) M(39) SB \
  M(40) M(41) M(42) M(43) SB M(44) M(45) M(46) M(47) SB \
  M(48) M(49) M(50) M(51) SB M(52) M(53) M(54) M(55) SB \
  M(56) M(57) M(58) M(59) SB M(60) M(61) M(62) M(63) SB
#define SB __builtin_amdgcn_sched_barrier(0);

#define DSTEP(B, I0, I1, I2, I3) {                                        \
    h8f hh_ = hp[B];                                                      \
    h2f c0_ = __builtin_shufflevector(hh_, hh_, 0, 1);                    \
    h2f c1_ = __builtin_shufflevector(hh_, hh_, 2, 3);                    \
    h2f c2_ = __builtin_shufflevector(hh_, hh_, 4, 5);                    \
    h2f c3_ = __builtin_shufflevector(hh_, hh_, 6, 7);                    \
    ar0 = __builtin_amdgcn_fdot2(wr##I0, c0_, ar0, false);                \
    az0 = __builtin_amdgcn_fdot2(wz##I0, c0_, az0, false);                \
    an0 = __builtin_amdgcn_fdot2(wn##I0, c0_, an0, false);                \
    ar1 = __builtin_amdgcn_fdot2(wr##I1, c1_, ar1, false);                \
    az1 = __builtin_amdgcn_fdot2(wz##I1, c1_, az1, false);                \
    an1 = __builtin_amdgcn_fdot2(wn##I1, c1_, an1, false);                \
    ar0 = __builtin_amdgcn_fdot2(wr##I2, c2_, ar0, false);                \
    az0 = __builtin_amdgcn_fdot2(wz##I2, c2_, az0, false);                \
    an0 = __builtin_amdgcn_fdot2(wn##I2, c2_, an0, false);                \
    ar1 = __builtin_amdgcn_fdot2(wr##I3, c3_, ar1, false);                \
    az1 = __builtin_amdgcn_fdot2(wz##I3, c3_, az1, false);                \
    an1 = __builtin_amdgcn_fdot2(wn##I3, c3_, an1, false); }

// ---------------- Phase 2: persistent GRU scan, one block per batch ----------
// ROUND-7 LESSON: the weight representation (array / ext-vector / named
// scalars) was NEVER the variable — VGPR_Count pinned at 128 across all three.
// Theory: __launch_bounds__ overrides amdgpu_waves_per_eu; its occupancy
// heuristic targets 4 waves/SIMD -> 128-reg budget -> the 192 weights can't be
// arch-resident no matter the representation (~240 extra move instrs/step,
// active-CU VALUBusy 71%). Fix: NO __launch_bounds__; declare geometry purely
// via amdgpu attributes: flat_work_group_size(512,512) (exact block size) +
// waves_per_eu(1,2) (allow as low as 1 wave/EU -> RA budget up to 256+ regs).
__global__ __attribute__((amdgpu_flat_work_group_size(512, 512)))
__attribute__((amdgpu_waves_per_eu(1, 2)))
void gru_scan(
    const __half* __restrict__ gx,   // [B, T, 768] fp16 (includes b_ih)
    const float*  __restrict__ Whh,  // [768, 256]
    const float*  __restrict__ bhh,  // [768]
    float* __restrict__ out)         // [B, T, 256]
{
  const int b = blockIdx.x;
  const int j = threadIdx.x;   // 0..511
  const int u = j >> 1;        // hidden unit 0..255
  const int p = j & 1;         // K-half

  // [buf][half][128 data + 8 pad]: 272B half-stride keeps the pair's two
  // broadcast addresses in different bank groups (round-5: conflicts -> 0).
  __shared__ __align__(16) _Float16 hbuf[2][2][136];

  // ---- weights: 3 gate rows x 128 cols (this lane's K-half) ----
  REP64(D3)
  {
    const float* rr = Whh + (size_t)u * DM + p * 128;
    const float* rz = rr + (size_t)DM * DM;
    const float* rn = rz + (size_t)DM * DM;
    REP64B4(L3)
  }
  const float br = bhh[u];
  const float bz = bhh[DM + u];
  const float bn = bhh[2 * DM + u];
  float hloc = 0.0f;

  if (j < DM) hbuf[0][j >> 7][j & 127] = (_Float16)0.0f;
  __syncthreads();

  const __half* gp = gx + (size_t)b * TSEQ * TG;
  float* outb = out + (size_t)b * TSEQ * DM;

  float gxr = __half2float(gp[u]);
  float gxz = __half2float(gp[DM + u]);
  float gxn = __half2float(gp[2 * DM + u]);

  for (int t = 0; t < TSEQ; ++t) {
    const int cur = t & 1;
    const h8f* hp = (const h8f*)(&hbuf[cur][p][0]);

    // prefetch next timestep's gx (hides under the dot loop)
    float nr = 0.f, nz = 0.f, nn = 0.f;
    if (t + 1 < TSEQ) {
      const __half* g1 = gp + TG;
      nr = __half2float(g1[u]);
      nz = __half2float(g1[DM + u]);
      nn = __half2float(g1[2 * DM + u]);
    }

    // ---- partial dots over this lane's 128 columns (192 fdot2) ----
    float ar0 = 0.f, ar1 = 0.f, az0 = 0.f, az1 = 0.f, an0 = 0.f, an1 = 0.f;
    DSTEP(0,  0,  1,  2,  3)  DSTEP(1,  4,  5,  6,  7)
    DSTEP(2,  8,  9,  10, 11) DSTEP(3,  12, 13, 14, 15)
    DSTEP(4,  16, 17, 18, 19) DSTEP(5,  20, 21, 22, 23)
    DSTEP(6,  24, 25, 26, 27) DSTEP(7,  28, 29, 30, 31)
    DSTEP(8,  32, 33, 34, 35) DSTEP(9,  36, 37, 38, 39)
    DSTEP(10, 40, 41, 42, 43) DSTEP(11, 44, 45, 46, 47)
    DSTEP(12, 48, 49, 50, 51) DSTEP(13, 52, 53, 54, 55)
    DSTEP(14, 56, 57, 58, 59) DSTEP(15, 60, 61, 62, 63)

    // ---- pair butterfly: both lanes get the full 256-wide sums ----
    float ar = dpp_xor1_add(ar0 + ar1);
    float az = dpp_xor1_add(az0 + az1);
    float an = dpp_xor1_add(an0 + an1);

    // ---- gates (redundant on both pair lanes; no LDS exchange) ----
    float r = __builtin_amdgcn_rcpf(1.0f + __expf(-(gxr + ar + br)));
    float z = __builtin_amdgcn_rcpf(1.0f + __expf(-(gxz + az + bz)));
    float a = gxn + r * (an + bn);
    float e = __expf(-2.0f * __builtin_fabsf(a));              // in (0,1]
    float n = __builtin_copysignf((1.0f - e) * __builtin_amdgcn_rcpf(1.0f + e), a);
    float hnew = n + z * (hloc - n);
    hloc = hnew;

    if (p == 0) {
      hbuf[cur ^ 1][u >> 7][u & 127] = (_Float16)hnew;
      outb[(size_t)t * DM + u] = hnew;
    }
    __syncthreads();   // writes to buf^1 visible before next iteration reads

    gp += TG;
    gxr = nr; gxz = nz; gxn = nn;
  }
}

extern "C" void kernel_launch(void* const* d_in, const int* in_sizes, int n_in,
                              void* d_out, int out_size, void* d_ws, size_t ws_size,
                              hipStream_t stream) {
  const float* x   = (const float*)d_in[0];
  const float* W1  = (const float*)d_in[1];
  const float* b1  = (const float*)d_in[2];
  const float* Wih = (const float*)d_in[3];
  const float* bih = (const float*)d_in[4];
  const float* Whh = (const float*)d_in[5];
  const float* bhh = (const float*)d_in[6];
  float* out = (float*)d_out;

  char* ws = (char*)d_ws;
  __half* h  = (__half*)ws;                                   // [32768,512] fp16
  size_t h_bytes = (size_t)MTOT * DI * sizeof(__half);
  h_bytes = (h_bytes + 255) & ~(size_t)255;
  __half* gxbuf = (__half*)(ws + h_bytes);                    // [32768,768] fp16

  dim3 blk(256);
  gemm_bias<false, true><<<dim3(DI / 128, MTOT / 128), blk, 0, stream>>>(
      x, W1, b1, h, MTOT, DI, DM);
  gemm_bias<true, false><<<dim3(TG / 128, MTOT / 128), blk, 0, stream>>>(
      h, Wih, bih, gxbuf, MTOT, TG, DI);
  gru_scan<<<NB, 512, 0, stream>>>(gxbuf, Whh, bhh, out);
}

// Round 9
// 4994.085 us; speedup vs baseline: 1.0052x; 1.0005x over previous
//
#include <hip/hip_runtime.h>
#include <hip/hip_fp16.h>
#include <hip/hip_bf16.h>

#define DM   256      // d_model
#define DI   512      // d_inner
#define TG   768      // 3*d_model
#define TSEQ 4096
#define NB   8
#define MTOT (NB*TSEQ) // 32768

typedef _Float16 h2f  __attribute__((ext_vector_type(2)));
typedef _Float16 h8f  __attribute__((ext_vector_type(8)));

// ---------------- Phase 1: tiled fp32 GEMM, C = act(A @ W^T + bias) in fp16 ----
template<bool A_HALF, bool GELU_ACT>
__global__ __launch_bounds__(256) void gemm_bias(
    const void* __restrict__ Ap, const float* __restrict__ W,
    const float* __restrict__ bias, __half* __restrict__ C,
    int M, int N, int K)
{
  __shared__ float As[16][132];   // transposed: [k][m]
  __shared__ float Ws[16][132];   // transposed: [k][n]
  const int tid = threadIdx.x;
  const int tx = tid & 15, ty = tid >> 4;
  const int m0 = blockIdx.y * 128;
  const int n0 = blockIdx.x * 128;

  float acc[8][8] = {};

  for (int k0 = 0; k0 < K; k0 += 16) {
    if constexpr (A_HALF) {
      const __half* A = (const __half*)Ap;
      int r = tid >> 1, seg = (tid & 1) * 8;
      float4 raw = *(const float4*)(A + (size_t)(m0 + r) * K + k0 + seg);
      const __half* hv = (const __half*)&raw;
      #pragma unroll
      for (int q = 0; q < 8; q++) As[seg + q][r] = __half2float(hv[q]);
    } else {
      const float* A = (const float*)Ap;
      #pragma unroll
      for (int rep = 0; rep < 2; rep++) {
        int r = (tid >> 2) + rep * 64;
        int seg = (tid & 3) * 4;
        float4 v = *(const float4*)(A + (size_t)(m0 + r) * K + k0 + seg);
        As[seg + 0][r] = v.x; As[seg + 1][r] = v.y;
        As[seg + 2][r] = v.z; As[seg + 3][r] = v.w;
      }
    }
    #pragma unroll
    for (int rep = 0; rep < 2; rep++) {
      int r = (tid >> 2) + rep * 64;
      int seg = (tid & 3) * 4;
      float4 v = *(const float4*)(W + (size_t)(n0 + r) * K + k0 + seg);
      Ws[seg + 0][r] = v.x; Ws[seg + 1][r] = v.y;
      Ws[seg + 2][r] = v.z; Ws[seg + 3][r] = v.w;
    }
    __syncthreads();
    #pragma unroll
    for (int kk = 0; kk < 16; ++kk) {
      float a[8], b[8];
      *(float4*)&a[0] = *(const float4*)&As[kk][ty * 8];
      *(float4*)&a[4] = *(const float4*)&As[kk][ty * 8 + 4];
      *(float4*)&b[0] = *(const float4*)&Ws[kk][tx * 8];
      *(float4*)&b[4] = *(const float4*)&Ws[kk][tx * 8 + 4];
      #pragma unroll
      for (int i = 0; i < 8; i++)
        #pragma unroll
        for (int j = 0; j < 8; j++)
          acc[i][j] += a[i] * b[j];
    }
    __syncthreads();
  }

  #pragma unroll
  for (int i = 0; i < 8; i++) {
    int m = m0 + ty * 8 + i;
    #pragma unroll
    for (int j = 0; j < 8; j++) {
      int n = n0 + tx * 8 + j;
      float v = acc[i][j] + bias[n];
      if constexpr (GELU_ACT) {
        v = 0.5f * v * (1.0f + erff(v * 0.70710678118654752f));  // exact GELU
      }
      C[(size_t)m * N + n] = __float2half(v);
    }
  }
}

// ---------------- DPP pair butterfly (lane 2u <-> 2u+1), VALU only -----------
__device__ __forceinline__ float dpp_xor1_add(float v) {
  int i = __builtin_bit_cast(int, v);
  int s = __builtin_amdgcn_update_dpp(i, i, 0xB1, 0xF, 0xF, true); // quad_perm [1,0,3,2]
  return v + __builtin_bit_cast(float, s);
}

// ---- weights as 192 NAMED scalar h2f locals --------------------------------
#define D3(i) h2f wr##i, wz##i, wn##i;
#define L3(i) { float2 f_;                                                     \
    f_ = *(const float2*)(rr + 2*(i)); wr##i[0]=(_Float16)f_.x; wr##i[1]=(_Float16)f_.y; \
    f_ = *(const float2*)(rz + 2*(i)); wz##i[0]=(_Float16)f_.x; wz##i[1]=(_Float16)f_.y; \
    f_ = *(const float2*)(rn + 2*(i)); wn##i[0]=(_Float16)f_.x; wn##i[1]=(_Float16)f_.y; }

#define REP64(M) \
  M(0)  M(1)  M(2)  M(3)  M(4)  M(5)  M(6)  M(7)  \
  M(8)  M(9)  M(10) M(11) M(12) M(13) M(14) M(15) \
  M(16) M(17) M(18) M(19) M(20) M(21) M(22) M(23) \
  M(24) M(25) M(26) M(27) M(28) M(29) M(30) M(31) \
  M(32) M(33) M(34) M(35) M(36) M(37) M(38) M(39) \
  M(40) M(41) M(42) M(43) M(44) M(45) M(46) M(47) \
  M(48) M(49) M(50) M(51) M(52) M(53) M(54) M(55) \
  M(56) M(57) M(58) M(59) M(60) M(61) M(62) M(63)

#define REP64B4(M) /* with sched_barrier every 4 to bound loads in flight */ \
  M(0)  M(1)  M(2)  M(3)  SB M(4)  M(5)  M(6)  M(7)  SB \
  M(8)  M(9)  M(10) M(11) SB M(12) M(13) M(14) M(15) SB \
  M(16) M(17) M(18) M(19) SB M(20) M(21) M(22) M(23) SB \
  M(24) M(25) M(26) M(27) SB M(28) M(29) M(30) M(31) SB \
  M(32) M(33) M(34) M(35) SB M(36) M(37) M(38) M(39) SB \
  M(40) M(41) M(42) M(43) SB M(44) M(45) M(46) M(47) SB \
  M(48) M(49) M(50) M(51) SB M(52) M(53) M(54) M(55) SB \
  M(56) M(57) M(58) M(59) SB M(60) M(61) M(62) M(63) SB
#define SB __builtin_amdgcn_sched_barrier(0);

#define DSTEP(B, I0, I1, I2, I3) {                                        \
    h8f hh_ = hp[B];                                                      \
    h2f c0_ = __builtin_shufflevector(hh_, hh_, 0, 1);                    \
    h2f c1_ = __builtin_shufflevector(hh_, hh_, 2, 3);                    \
    h2f c2_ = __builtin_shufflevector(hh_, hh_, 4, 5);                    \
    h2f c3_ = __builtin_shufflevector(hh_, hh_, 6, 7);                    \
    ar0 = __builtin_amdgcn_fdot2(wr##I0, c0_, ar0, false);                \
    az0 = __builtin_amdgcn_fdot2(wz##I0, c0_, az0, false);                \
    an0 = __builtin_amdgcn_fdot2(wn##I0, c0_, an0, false);                \
    ar1 = __builtin_amdgcn_fdot2(wr##I1, c1_, ar1, false);                \
    az1 = __builtin_amdgcn_fdot2(wz##I1, c1_, az1, false);                \
    an1 = __builtin_amdgcn_fdot2(wn##I1, c1_, an1, false);                \
    ar0 = __builtin_amdgcn_fdot2(wr##I2, c2_, ar0, false);                \
    az0 = __builtin_amdgcn_fdot2(wz##I2, c2_, az0, false);                \
    an0 = __builtin_amdgcn_fdot2(wn##I2, c2_, an0, false);                \
    ar1 = __builtin_amdgcn_fdot2(wr##I3, c3_, ar1, false);                \
    az1 = __builtin_amdgcn_fdot2(wz##I3, c3_, az1, false);                \
    an1 = __builtin_amdgcn_fdot2(wn##I3, c3_, an1, false); }

// ---------------- Phase 2: persistent GRU scan, one block per batch ----------
// ROUND-8 LESSON: VGPR_Count pinned at 128 across launch_bounds variants,
// waves_per_eu attrs, AND weight representations. Pattern: 768thr->84=512/6,
// 512thr->128=512/4 — the RA's occupancy heuristic targets 2 BLOCKS/CU no
// matter what we declare. New lever: make 1 block/CU a COMPILE-TIME fact via
// static LDS. 96KB static LDS (160KB pool) -> max 1 block/CU -> 8 waves ->
// 2 waves/SIMD -> register budget 512/2 = 256, fits the 192-weight set (~225
// live) with slack. (128KB static LDS in plain HIP is proven on gfx950.)
__global__ __attribute__((amdgpu_flat_work_group_size(512, 512)))
__attribute__((amdgpu_waves_per_eu(1, 2)))
void gru_scan(
    const __half* __restrict__ gx,   // [B, T, 768] fp16 (includes b_ih)
    const float*  __restrict__ Whh,  // [768, 256]
    const float*  __restrict__ bhh,  // [768]
    float* __restrict__ out)         // [B, T, 256]
{
  const int b = blockIdx.x;
  const int j = threadIdx.x;   // 0..511
  const int u = j >> 1;        // hidden unit 0..255
  const int p = j & 1;         // K-half

  // 96 KB static pool: forces 1 block/CU at compile time (the actual state
  // buffer lives in its first 1088 B; layout [buf][half][128 data + 8 pad],
  // 272B half-stride keeps the pair's broadcast addresses conflict-free).
  __shared__ __align__(16) _Float16 lds_pool[49152];
  typedef _Float16 (*hbuf_t)[2][136];
  hbuf_t hbuf = (hbuf_t)lds_pool;

  // ---- weights: 3 gate rows x 128 cols (this lane's K-half) ----
  REP64(D3)
  {
    const float* rr = Whh + (size_t)u * DM + p * 128;
    const float* rz = rr + (size_t)DM * DM;
    const float* rn = rz + (size_t)DM * DM;
    REP64B4(L3)
  }
  const float br = bhh[u];
  const float bz = bhh[DM + u];
  const float bn = bhh[2 * DM + u];
  float hloc = 0.0f;

  if (j < DM) hbuf[0][j >> 7][j & 127] = (_Float16)0.0f;
  __syncthreads();

  const __half* gp = gx + (size_t)b * TSEQ * TG;
  float* outb = out + (size_t)b * TSEQ * DM;

  float gxr = __half2float(gp[u]);
  float gxz = __half2float(gp[DM + u]);
  float gxn = __half2float(gp[2 * DM + u]);

  for (int t = 0; t < TSEQ; ++t) {
    const int cur = t & 1;
    const h8f* hp = (const h8f*)(&hbuf[cur][p][0]);

    // prefetch next timestep's gx (hides under the dot loop)
    float nr = 0.f, nz = 0.f, nn = 0.f;
    if (t + 1 < TSEQ) {
      const __half* g1 = gp + TG;
      nr = __half2float(g1[u]);
      nz = __half2float(g1[DM + u]);
      nn = __half2float(g1[2 * DM + u]);
    }

    // ---- partial dots over this lane's 128 columns (192 fdot2) ----
    float ar0 = 0.f, ar1 = 0.f, az0 = 0.f, az1 = 0.f, an0 = 0.f, an1 = 0.f;
    DSTEP(0,  0,  1,  2,  3)  DSTEP(1,  4,  5,  6,  7)
    DSTEP(2,  8,  9,  10, 11) DSTEP(3,  12, 13, 14, 15)
    DSTEP(4,  16, 17, 18, 19) DSTEP(5,  20, 21, 22, 23)
    DSTEP(6,  24, 25, 26, 27) DSTEP(7,  28, 29, 30, 31)
    DSTEP(8,  32, 33, 34, 35) DSTEP(9,  36, 37, 38, 39)
    DSTEP(10, 40, 41, 42, 43) DSTEP(11, 44, 45, 46, 47)
    DSTEP(12, 48, 49, 50, 51) DSTEP(13, 52, 53, 54, 55)
    DSTEP(14, 56, 57, 58, 59) DSTEP(15, 60, 61, 62, 63)

    // ---- pair butterfly: both lanes get the full 256-wide sums ----
    float ar = dpp_xor1_add(ar0 + ar1);
    float az = dpp_xor1_add(az0 + az1);
    float an = dpp_xor1_add(an0 + an1);

    // ---- gates (redundant on both pair lanes; no LDS exchange) ----
    float r = __builtin_amdgcn_rcpf(1.0f + __expf(-(gxr + ar + br)));
    float z = __builtin_amdgcn_rcpf(1.0f + __expf(-(gxz + az + bz)));
    float a = gxn + r * (an + bn);
    float e = __expf(-2.0f * __builtin_fabsf(a));              // in (0,1]
    float n = __builtin_copysignf((1.0f - e) * __builtin_amdgcn_rcpf(1.0f + e), a);
    float hnew = n + z * (hloc - n);
    hloc = hnew;

    if (p == 0) {
      hbuf[cur ^ 1][u >> 7][u & 127] = (_Float16)hnew;
      outb[(size_t)t * DM + u] = hnew;
    }
    __syncthreads();   // writes to buf^1 visible before next iteration reads

    gp += TG;
    gxr = nr; gxz = nz; gxn = nn;
  }
}

extern "C" void kernel_launch(void* const* d_in, const int* in_sizes, int n_in,
                              void* d_out, int out_size, void* d_ws, size_t ws_size,
                              hipStream_t stream) {
  const float* x   = (const float*)d_in[0];
  const float* W1  = (const float*)d_in[1];
  const float* b1  = (const float*)d_in[2];
  const float* Wih = (const float*)d_in[3];
  const float* bih = (const float*)d_in[4];
  const float* Whh = (const float*)d_in[5];
  const float* bhh = (const float*)d_in[6];
  float* out = (float*)d_out;

  char* ws = (char*)d_ws;
  __half* h  = (__half*)ws;                                   // [32768,512] fp16
  size_t h_bytes = (size_t)MTOT * DI * sizeof(__half);
  h_bytes = (h_bytes + 255) & ~(size_t)255;
  __half* gxbuf = (__half*)(ws + h_bytes);                    // [32768,768] fp16

  dim3 blk(256);
  gemm_bias<false, true><<<dim3(DI / 128, MTOT / 128), blk, 0, stream>>>(
      x, W1, b1, h, MTOT, DI, DM);
  gemm_bias<true, false><<<dim3(TG / 128, MTOT / 128), blk, 0, stream>>>(
      h, Wih, bih, gxbuf, MTOT, TG, DI);
  gru_scan<<<NB, 512, 0, stream>>>(gxbuf, Whh, bhh, out);
}